// Round 1
// baseline (342.477 us; speedup 1.0000x reference)
//
#include <hip/hip_runtime.h>
#include <hip/hip_bf16.h>

// QuantizedLinear: out[n][o] = scale[o] * dot(x[n,:], (q[o,:]-8)) + bias[o]
// Strategy: unpack int4 weights to EXACT bf16 integers (-8..7), convert x to
// bf16, run m97-style 128x128 bf16 MFMA GEMM (B^T layout is natural: W is
// [out][in]), fuse scale+bias in the epilogue.

typedef __attribute__((ext_vector_type(8))) __bf16 bf16x8;
typedef __attribute__((ext_vector_type(4))) float f32x4;

#define GLOBAL_AS __attribute__((address_space(1)))
#define LDS_AS __attribute__((address_space(3)))

#define BM 128
#define BN 128
#define BK 64

__device__ inline unsigned short f32_to_bf16(float f) {
    unsigned int u = __float_as_uint(f);
    unsigned int r = (u + 0x7FFFu + ((u >> 16) & 1u)) >> 16;
    return (unsigned short)r;
}

// ---- preprocessing: x fp32 -> bf16 ----
__global__ void cvt_x(const float* __restrict__ x, unsigned short* __restrict__ xb, int n) {
    int i = (blockIdx.x * blockDim.x + threadIdx.x) * 4;
    if (i >= n) return;
    float4 v = *(const float4*)(x + i);
    union { unsigned short h[4]; uint2 u; } o;
    o.h[0] = f32_to_bf16(v.x);
    o.h[1] = f32_to_bf16(v.y);
    o.h[2] = f32_to_bf16(v.z);
    o.h[3] = f32_to_bf16(v.w);
    *(uint2*)(xb + i) = o.u;
}

// ---- preprocessing: packed nibbles -> bf16 integer weights (q-8, exact) ----
__global__ void unpack_w(const int* __restrict__ wp, unsigned short* __restrict__ wb, int n_packed) {
    int i = (blockIdx.x * blockDim.x + threadIdx.x) * 4;
    if (i >= n_packed) return;
    int4 v = *(const int4*)(wp + i);
    int vals[4] = {v.x, v.y, v.z, v.w};
    union { unsigned short h[8]; uint4 u; } o;
#pragma unroll
    for (int t = 0; t < 4; ++t) {
        o.h[2 * t]     = f32_to_bf16((float)((vals[t] & 0xF) - 8));
        o.h[2 * t + 1] = f32_to_bf16((float)(((vals[t] >> 4) & 0xF) - 8));
    }
    *(uint4*)(wb + 2 * i) = o.u;
}

// ---- main GEMM: C[m][n] = sum_k A[m][k]*B[n][k]; epilogue scale/bias ----
// A = xb [M][K] bf16, B = wb [N][K] bf16 (N = out features)
__global__ __launch_bounds__(256) void gemm_bt(
    const unsigned short* __restrict__ A,
    const unsigned short* __restrict__ B,
    const float* __restrict__ scales,
    const float* __restrict__ bias,
    float* __restrict__ C,
    int M, int N, int K)
{
    __shared__ unsigned short As[BM * BK];  // 16 KB
    __shared__ unsigned short Bs[BN * BK];  // 16 KB

    const int tid  = threadIdx.x;
    const int wave = tid >> 6;
    const int lane = tid & 63;
    const int wm = wave >> 1;   // wave row (0..1)
    const int wn = wave & 1;    // wave col (0..1)
    const int m0 = blockIdx.y * BM;
    const int n0 = blockIdx.x * BN;

    f32x4 acc[4][4];
#pragma unroll
    for (int i = 0; i < 4; ++i)
#pragma unroll
        for (int j = 0; j < 4; ++j)
            acc[i][j] = (f32x4){0.f, 0.f, 0.f, 0.f};

    // staging: each thread moves one 16B chunk (8 bf16) per call, 4 calls per tile
    const int srow = tid >> 3;        // 0..31
    const int scol = (tid & 7) * 8;   // element column (8 bf16 per chunk)

    const unsigned short* Ag = A + (size_t)(m0 + srow) * K + scol;
    const unsigned short* Bg = B + (size_t)(n0 + srow) * K + scol;

    const int am = lane & 15;   // fragment row (m or n within 16-tile)
    const int aq = lane >> 4;   // quad -> k block of 8

    for (int k0 = 0; k0 < K; k0 += BK) {
#pragma unroll
        for (int j = 0; j < 4; ++j) {
            __builtin_amdgcn_global_load_lds(
                (const GLOBAL_AS void*)(Ag + (size_t)(j * 32) * K + k0),
                (LDS_AS void*)(As + tid * 8 + j * 2048), 16, 0, 0);
        }
#pragma unroll
        for (int j = 0; j < 4; ++j) {
            __builtin_amdgcn_global_load_lds(
                (const GLOBAL_AS void*)(Bg + (size_t)(j * 32) * K + k0),
                (LDS_AS void*)(Bs + tid * 8 + j * 2048), 16, 0, 0);
        }
        __syncthreads();

#pragma unroll
        for (int kk = 0; kk < BK; kk += 32) {
            bf16x8 af[4], bfr[4];
#pragma unroll
            for (int i = 0; i < 4; ++i)
                af[i] = *(const bf16x8*)&As[(wm * 64 + i * 16 + am) * BK + kk + aq * 8];
#pragma unroll
            for (int j = 0; j < 4; ++j)
                bfr[j] = *(const bf16x8*)&Bs[(wn * 64 + j * 16 + am) * BK + kk + aq * 8];
#pragma unroll
            for (int i = 0; i < 4; ++i)
#pragma unroll
                for (int j = 0; j < 4; ++j)
                    acc[i][j] = __builtin_amdgcn_mfma_f32_16x16x32_bf16(af[i], bfr[j], acc[i][j], 0, 0, 0);
        }
        __syncthreads();
    }

    // epilogue: C/D layout col=lane&15, row=(lane>>4)*4+reg  [verified m89/m91]
    const int cq = lane >> 4;
    const int cc = lane & 15;
#pragma unroll
    for (int j = 0; j < 4; ++j) {
        const int col = n0 + wn * 64 + j * 16 + cc;
        const float s = scales[col];
        const float b = bias[col];
#pragma unroll
        for (int i = 0; i < 4; ++i) {
            const int rowb = m0 + wm * 64 + i * 16 + cq * 4;
#pragma unroll
            for (int r = 0; r < 4; ++r) {
                C[(size_t)(rowb + r) * N + col] = acc[i][j][r] * s + b;
            }
        }
    }
}

// ---- correctness fallback if workspace is too small ----
__global__ void naive_kernel(const float* __restrict__ x, const int* __restrict__ wp,
                             const float* __restrict__ sc, const float* __restrict__ bs,
                             float* __restrict__ out, int NR, int OUTF, int INF) {
    int idx = blockIdx.x * 256 + threadIdx.x;
    if (idx >= NR * OUTF) return;
    int n = idx / OUTF, o = idx - n * OUTF;
    const float* xr = x + (size_t)n * INF;
    const int* wr = wp + (size_t)o * (INF / 2);
    float acc = 0.f;
    for (int c = 0; c < INF / 2; ++c) {
        int v = wr[c];
        acc += xr[2 * c] * (float)((v & 0xF) - 8) + xr[2 * c + 1] * (float)(((v >> 4) & 0xF) - 8);
    }
    out[idx] = acc * sc[o] + bs[o];
}

extern "C" void kernel_launch(void* const* d_in, const int* in_sizes, int n_in,
                              void* d_out, int out_size, void* d_ws, size_t ws_size,
                              hipStream_t stream) {
    const float* x      = (const float*)d_in[0];
    const int*   wp     = (const int*)d_in[1];
    const float* scales = (const float*)d_in[2];
    const float* bias   = (const float*)d_in[3];
    float* out = (float*)d_out;

    const int OUTF = in_sizes[2];                    // 4096
    const int INF  = (2 * in_sizes[1]) / OUTF;       // 4096
    const int NR   = in_sizes[0] / INF;              // 4096

    unsigned short* xb = (unsigned short*)d_ws;
    unsigned short* wb = xb + (size_t)NR * INF;
    const size_t need = ((size_t)NR * INF + (size_t)OUTF * INF) * sizeof(unsigned short);

    if (ws_size >= need && (NR % BM) == 0 && (OUTF % BN) == 0 && (INF % BK) == 0) {
        int nx = NR * INF;
        cvt_x<<<(nx / 4 + 255) / 256, 256, 0, stream>>>(x, xb, nx);
        int np = in_sizes[1];
        unpack_w<<<(np / 4 + 255) / 256, 256, 0, stream>>>(wp, wb, np);
        dim3 grid(OUTF / BN, NR / BM);
        gemm_bt<<<grid, 256, 0, stream>>>(xb, wb, scales, bias, out, NR, OUTF, INF);
    } else {
        int total = NR * OUTF;
        naive_kernel<<<(total + 255) / 256, 256, 0, stream>>>(x, wp, scales, bias, out, NR, OUTF, INF);
    }
}

// Round 2
// 304.040 us; speedup vs baseline: 1.1264x; 1.1264x over previous
//
#include <hip/hip_runtime.h>
#include <hip/hip_bf16.h>

// QuantizedLinear: out[n][o] = scale[o] * dot(x[n,:], (q[o,:]-8)) + bias[o]
// R1: XOR-swizzled LDS (kb ^= row&7) to kill the 16-way bank conflicts that
// the 128B-row layout caused (R0: SQ_LDS_BANK_CONFLICT=5e7). Swizzle is
// applied to the GLOBAL source column during global_load_lds staging (the
// LDS dest must stay base+lane*16), and undone by XOR on the fragment reads.
// Prep kernels grid-strided + widened.

typedef __attribute__((ext_vector_type(8))) __bf16 bf16x8;
typedef __attribute__((ext_vector_type(4))) float f32x4;

#define GLOBAL_AS __attribute__((address_space(1)))
#define LDS_AS __attribute__((address_space(3)))

#define BM 128
#define BN 128
#define BK 64

__device__ inline unsigned short f32_to_bf16(float f) {
    unsigned int u = __float_as_uint(f);
    unsigned int r = (u + 0x7FFFu + ((u >> 16) & 1u)) >> 16;
    return (unsigned short)r;
}

// ---- preprocessing: x fp32 -> bf16 (8 elems/thread, grid-stride) ----
__global__ void cvt_x(const float* __restrict__ x, unsigned short* __restrict__ xb, int n8) {
    const int stride = gridDim.x * blockDim.x;
    for (int i = blockIdx.x * blockDim.x + threadIdx.x; i < n8; i += stride) {
        float4 a = ((const float4*)x)[2 * i];
        float4 b = ((const float4*)x)[2 * i + 1];
        union { unsigned short h[8]; uint4 u; } o;
        o.h[0] = f32_to_bf16(a.x); o.h[1] = f32_to_bf16(a.y);
        o.h[2] = f32_to_bf16(a.z); o.h[3] = f32_to_bf16(a.w);
        o.h[4] = f32_to_bf16(b.x); o.h[5] = f32_to_bf16(b.y);
        o.h[6] = f32_to_bf16(b.z); o.h[7] = f32_to_bf16(b.w);
        ((uint4*)xb)[i] = o.u;
    }
}

// ---- preprocessing: packed nibbles -> bf16 ints (q-8 exact), grid-stride ----
__global__ void unpack_w(const int* __restrict__ wp, unsigned short* __restrict__ wb, int n4) {
    const int stride = gridDim.x * blockDim.x;
    for (int i = blockIdx.x * blockDim.x + threadIdx.x; i < n4; i += stride) {
        int4 v = ((const int4*)wp)[i];
        int vals[4] = {v.x, v.y, v.z, v.w};
        union { unsigned short h[8]; uint4 u; } o;
#pragma unroll
        for (int t = 0; t < 4; ++t) {
            o.h[2 * t]     = f32_to_bf16((float)((vals[t] & 0xF) - 8));
            o.h[2 * t + 1] = f32_to_bf16((float)(((vals[t] >> 4) & 0xF) - 8));
        }
        ((uint4*)wb)[i] = o.u;
    }
}

// ---- main GEMM: C[m][n] = sum_k A[m][k]*B[n][k]; epilogue scale/bias ----
__global__ __launch_bounds__(256) void gemm_bt(
    const unsigned short* __restrict__ A,
    const unsigned short* __restrict__ B,
    const float* __restrict__ scales,
    const float* __restrict__ bias,
    float* __restrict__ C,
    int M, int N, int K)
{
    __shared__ unsigned short As[BM * BK];  // 16 KB
    __shared__ unsigned short Bs[BN * BK];  // 16 KB

    const int tid  = threadIdx.x;
    const int wave = tid >> 6;
    const int lane = tid & 63;
    const int wm = wave >> 1;
    const int wn = wave & 1;
    const int m0 = blockIdx.y * BM;
    const int n0 = blockIdx.x * BN;

    f32x4 acc[4][4];
#pragma unroll
    for (int i = 0; i < 4; ++i)
#pragma unroll
        for (int j = 0; j < 4; ++j)
            acc[i][j] = (f32x4){0.f, 0.f, 0.f, 0.f};

    // staging: thread tid loads 16B landing at LDS slot (row = tid>>3 (+32j),
    // kb = tid&7). XOR-swizzle: that slot holds global k-block kb ^ (row&7).
    const int srow = tid >> 3;                         // 0..31
    const int scol = ((tid & 7) ^ (srow & 7)) * 8;     // swizzled global column

    const unsigned short* Ag = A + (size_t)(m0 + srow) * K + scol;
    const unsigned short* Bg = B + (size_t)(n0 + srow) * K + scol;

    const int am = lane & 15;   // fragment row within 16-tile
    const int aq = lane >> 4;   // quad -> k sub-block of 8
    const int axr = am & 7;     // xor factor for swizzled reads

    for (int k0 = 0; k0 < K; k0 += BK) {
#pragma unroll
        for (int j = 0; j < 4; ++j) {
            __builtin_amdgcn_global_load_lds(
                (const GLOBAL_AS void*)(Ag + (size_t)(j * 32) * K + k0),
                (LDS_AS void*)(As + tid * 8 + j * 2048), 16, 0, 0);
        }
#pragma unroll
        for (int j = 0; j < 4; ++j) {
            __builtin_amdgcn_global_load_lds(
                (const GLOBAL_AS void*)(Bg + (size_t)(j * 32) * K + k0),
                (LDS_AS void*)(Bs + tid * 8 + j * 2048), 16, 0, 0);
        }
        __syncthreads();

#pragma unroll
        for (int kk = 0; kk < BK; kk += 32) {
            const int kb = kk >> 3;  // global k-block base (0 or 4)
            bf16x8 af[4], bfr[4];
#pragma unroll
            for (int i = 0; i < 4; ++i) {
                const int row = wm * 64 + i * 16 + am;
                af[i] = *(const bf16x8*)&As[row * BK + (((kb + aq) ^ axr) << 3)];
            }
#pragma unroll
            for (int j = 0; j < 4; ++j) {
                const int row = wn * 64 + j * 16 + am;
                bfr[j] = *(const bf16x8*)&Bs[row * BK + (((kb + aq) ^ axr) << 3)];
            }
#pragma unroll
            for (int i = 0; i < 4; ++i)
#pragma unroll
                for (int j = 0; j < 4; ++j)
                    acc[i][j] = __builtin_amdgcn_mfma_f32_16x16x32_bf16(af[i], bfr[j], acc[i][j], 0, 0, 0);
        }
        __syncthreads();
    }

    // epilogue: C/D layout col=lane&15, row=(lane>>4)*4+reg
    const int cq = lane >> 4;
    const int cc = lane & 15;
#pragma unroll
    for (int j = 0; j < 4; ++j) {
        const int col = n0 + wn * 64 + j * 16 + cc;
        const float s = scales[col];
        const float b = bias[col];
#pragma unroll
        for (int i = 0; i < 4; ++i) {
            const int rowb = m0 + wm * 64 + i * 16 + cq * 4;
#pragma unroll
            for (int r = 0; r < 4; ++r) {
                C[(size_t)(rowb + r) * N + col] = acc[i][j][r] * s + b;
            }
        }
    }
}

// ---- correctness fallback if workspace is too small ----
__global__ void naive_kernel(const float* __restrict__ x, const int* __restrict__ wp,
                             const float* __restrict__ sc, const float* __restrict__ bs,
                             float* __restrict__ out, int NR, int OUTF, int INF) {
    int idx = blockIdx.x * 256 + threadIdx.x;
    if (idx >= NR * OUTF) return;
    int n = idx / OUTF, o = idx - n * OUTF;
    const float* xr = x + (size_t)n * INF;
    const int* wr = wp + (size_t)o * (INF / 2);
    float acc = 0.f;
    for (int c = 0; c < INF / 2; ++c) {
        int v = wr[c];
        acc += xr[2 * c] * (float)((v & 0xF) - 8) + xr[2 * c + 1] * (float)(((v >> 4) & 0xF) - 8);
    }
    out[idx] = acc * sc[o] + bs[o];
}

extern "C" void kernel_launch(void* const* d_in, const int* in_sizes, int n_in,
                              void* d_out, int out_size, void* d_ws, size_t ws_size,
                              hipStream_t stream) {
    const float* x      = (const float*)d_in[0];
    const int*   wp     = (const int*)d_in[1];
    const float* scales = (const float*)d_in[2];
    const float* bias   = (const float*)d_in[3];
    float* out = (float*)d_out;

    const int OUTF = in_sizes[2];
    const int INF  = (2 * in_sizes[1]) / OUTF;
    const int NR   = in_sizes[0] / INF;

    unsigned short* xb = (unsigned short*)d_ws;
    unsigned short* wb = xb + (size_t)NR * INF;
    const size_t need = ((size_t)NR * INF + (size_t)OUTF * INF) * sizeof(unsigned short);

    if (ws_size >= need && (NR % BM) == 0 && (OUTF % BN) == 0 && (INF % BK) == 0
        && (in_sizes[0] % 8) == 0 && (in_sizes[1] % 4) == 0) {
        cvt_x<<<1024, 256, 0, stream>>>(x, xb, in_sizes[0] / 8);
        unpack_w<<<1024, 256, 0, stream>>>(wp, wb, in_sizes[1] / 4);
        dim3 grid(OUTF / BN, NR / BM);
        gemm_bt<<<grid, 256, 0, stream>>>(xb, wb, scales, bias, out, NR, OUTF, INF);
    } else {
        int total = NR * OUTF;
        naive_kernel<<<(total + 255) / 256, 256, 0, stream>>>(x, wp, scales, bias, out, NR, OUTF, INF);
    }
}